// Round 2
// 351.649 us; speedup vs baseline: 1.0584x; 1.0584x over previous
//
#include <hip/hip_runtime.h>
#include <hip/hip_bf16.h>
#include <math.h>

#define HIDDEN 512
#define MAX_LEN 4096
#define BATCH 32

// Native vector type for nontemporal builtins (HIP's float4 is a class and
// __builtin_nontemporal_load rejects it).
typedef float f32x4 __attribute__((ext_vector_type(4)));

// Kernel 1: v[b,h] = sum_o hidden[b,o] * W[o,h]   (v = hidden @ W)
// grid = 32 b * 8 h-segments = 256 blocks, 256 threads.
// Thread (og = tid>>6, hl = tid&63) computes partial over o in [og*128, og*128+128)
// for h = seg*64 + hl; LDS-reduce the 4 o-partials.
__global__ __launch_bounds__(256) void proj_hidden_kernel(
    const float* __restrict__ hidden,  // [1,B,H]
    const float* __restrict__ W,       // [H,H] row-major (o,h)
    float* __restrict__ v)             // [B,H]
{
    __shared__ float hs[HIDDEN];
    __shared__ float red[256];
    const int b   = blockIdx.x >> 3;
    const int seg = blockIdx.x & 7;
    const int tid = threadIdx.x;
    const int og  = tid >> 6;
    const int hl  = tid & 63;
    const int h   = seg * 64 + hl;

    hs[tid]       = hidden[b * HIDDEN + tid];
    hs[tid + 256] = hidden[b * HIDDEN + tid + 256];
    __syncthreads();

    float acc = 0.f;
    const int o0 = og * 128;
#pragma unroll 8
    for (int o = o0; o < o0 + 128; ++o) {
        acc += hs[o] * W[o * HIDDEN + h];
    }
    red[tid] = acc;
    __syncthreads();
    if (tid < 64) {
        v[b * HIDDEN + seg * 64 + tid] =
            red[tid] + red[tid + 64] + red[tid + 128] + red[tid + 192];
    }
}

// Kernel 2: energies[b,l] = sum_h v[b,h] * enc[l,b,h]
// One wave per (b, 8 consecutive l). 16384 waves -> 4096 blocks of 256.
// enc is read exactly once ever -> non-temporal (evict-first) loads.
// Reduction: butterfly bits0-2 (24 shfl), per-slot select (7 sel), 3 shfl.
__global__ __launch_bounds__(256) void energy_kernel(
    const float* __restrict__ enc,   // [L,B,H]
    const float* __restrict__ v,     // [B,H]
    float* __restrict__ energies)    // [B,L]
{
    const int wave = blockIdx.x * 4 + (threadIdx.x >> 6);
    const int lane = threadIdx.x & 63;
    const int b  = wave & (BATCH - 1);
    const int lg = wave >> 5;        // 0..511
    const int l0 = lg * 8;

    const f32x4* vb = (const f32x4*)(v + b * HIDDEN);
    const f32x4 v0 = vb[lane];
    const f32x4 v1 = vb[lane + 64];

    float acc[8];
#pragma unroll
    for (int i = 0; i < 8; ++i) {
        const f32x4* e = (const f32x4*)(enc + (size_t)((l0 + i) * BATCH + b) * HIDDEN);
        const f32x4 e0 = __builtin_nontemporal_load(&e[lane]);
        const f32x4 e1 = __builtin_nontemporal_load(&e[lane + 64]);
        acc[i] = e0.x * v0.x + e0.y * v0.y + e0.z * v0.z + e0.w * v0.w
               + e1.x * v1.x + e1.y * v1.y + e1.z * v1.z + e1.w * v1.w;
    }

    // Stage 1: reduce within each contiguous 8-lane group (bits 0-2).
    // After this, lane L holds S_i(g) for all i, where g = L>>3.
#pragma unroll
    for (int i = 0; i < 8; ++i) {
        acc[i] += __shfl_xor(acc[i], 1, 64);
        acc[i] += __shfl_xor(acc[i], 2, 64);
        acc[i] += __shfl_xor(acc[i], 4, 64);
    }
    // Stage 2: lane slot j = lane&7 takes value index j (compile-time indexed selects).
    const int slot = lane & 7;
    float val = acc[0];
#pragma unroll
    for (int i = 1; i < 8; ++i) val = (slot == i) ? acc[i] : val;
    // Stage 3: sum across the 8 groups (bits 3-5). Every lane L ends with total_{L&7}.
    val += __shfl_xor(val, 8, 64);
    val += __shfl_xor(val, 16, 64);
    val += __shfl_xor(val, 32, 64);

    if (lane < 8) energies[b * MAX_LEN + l0 + lane] = val;
}

// Kernel 3: row softmax over L per b. grid = B blocks, 256 threads, 16 elems/thread.
__global__ __launch_bounds__(256) void softmax_kernel(
    const float* __restrict__ energies,  // [B,L]
    float* __restrict__ out)             // [B,1,L]
{
    const int b = blockIdx.x;
    const int tid = threadIdx.x;
    const int wid = tid >> 6, lane = tid & 63;
    const float4* r4 = (const float4*)(energies + b * MAX_LEN);

    float4 x[4];
    float m = -INFINITY;
#pragma unroll
    for (int i = 0; i < 4; ++i) {
        x[i] = r4[tid + 256 * i];
        m = fmaxf(m, fmaxf(fmaxf(x[i].x, x[i].y), fmaxf(x[i].z, x[i].w)));
    }
#pragma unroll
    for (int off = 32; off; off >>= 1) m = fmaxf(m, __shfl_xor(m, off, 64));

    __shared__ float sm[4];
    __shared__ float ss[4];
    if (lane == 0) sm[wid] = m;
    __syncthreads();
    m = fmaxf(fmaxf(sm[0], sm[1]), fmaxf(sm[2], sm[3]));

    float s = 0.f;
#pragma unroll
    for (int i = 0; i < 4; ++i) {
        x[i].x = __expf(x[i].x - m);
        x[i].y = __expf(x[i].y - m);
        x[i].z = __expf(x[i].z - m);
        x[i].w = __expf(x[i].w - m);
        s += x[i].x + x[i].y + x[i].z + x[i].w;
    }
#pragma unroll
    for (int off = 32; off; off >>= 1) s += __shfl_xor(s, off, 64);
    if (lane == 0) ss[wid] = s;
    __syncthreads();
    s = ss[0] + ss[1] + ss[2] + ss[3];
    const float inv = 1.f / s;

    float4* o4 = (float4*)(out + b * MAX_LEN);
#pragma unroll
    for (int i = 0; i < 4; ++i) {
        float4 y = x[i];
        y.x *= inv; y.y *= inv; y.z *= inv; y.w *= inv;
        o4[tid + 256 * i] = y;
    }
}

extern "C" void kernel_launch(void* const* d_in, const int* in_sizes, int n_in,
                              void* d_out, int out_size, void* d_ws, size_t ws_size,
                              hipStream_t stream) {
    const float* hidden = (const float*)d_in[0];   // [1,B,H]
    const float* enc    = (const float*)d_in[1];   // [L,B,H]
    const float* W      = (const float*)d_in[2];   // [H,H]
    // d_in[3] = bias: constant per softmax row -> softmax-invariant -> unused.
    float* out = (float*)d_out;                    // [B,1,L]

    float* v        = (float*)d_ws;                // B*H floats
    float* energies = v + BATCH * HIDDEN;          // B*L floats

    proj_hidden_kernel<<<BATCH * 8, 256, 0, stream>>>(hidden, W, v);
    energy_kernel<<<(BATCH * (MAX_LEN / 8)) / 4, 256, 0, stream>>>(enc, v, energies);
    softmax_kernel<<<BATCH, 256, 0, stream>>>(energies, out);
}